// Round 13
// baseline (161.039 us; speedup 1.0000x reference)
//
#include <hip/hip_runtime.h>

typedef float f32x4 __attribute__((ext_vector_type(4)));
typedef short s16x8 __attribute__((ext_vector_type(8)));
typedef unsigned short u16;
typedef unsigned short u16x8 __attribute__((ext_vector_type(8)));

__device__ __forceinline__ u16 f2bf(float f) {
  unsigned u = __builtin_bit_cast(unsigned, f);
  u += 0x7fffu + ((u >> 16) & 1u);   // RNE
  return (u16)(u >> 16);
}

__device__ __forceinline__ unsigned cvt_pk_bf16(float a, float b) {
  unsigned r;
  asm("v_cvt_pk_bf16_f32 %0, %1, %2" : "=v"(r) : "v"(a), "v"(b));
  return r;   // lo = bf16(a), hi = bf16(b), RNE
}

#define AS1 __attribute__((address_space(1)))
#define AS3 __attribute__((address_space(3)))
#define GLD16(g, l) __builtin_amdgcn_global_load_lds((const AS1 unsigned int*)(g), (AS3 unsigned int*)(l), 16, 0, 0)

// Q is pre-scaled by log2(e)/64 at projection so attn uses exp2 directly.
#define CEXP 0.0225421101f

// ---------------- Kernel 0: prepack W -> bf16 (chunk-major, swizzled) + zero sems ----
__global__ __launch_bounds__(256) void prepack_w(
    const float* __restrict__ wq, const float* __restrict__ wk, const float* __restrict__ wv,
    u16* __restrict__ Wpk, unsigned* __restrict__ sem)
{
  if (blockIdx.x == 0 && threadIdx.x < 16) sem[threadIdx.x] = 0;
  const int d = blockIdx.x;          // 0..191
  const int t = threadIdx.x;         // kc = t>>3 (0..31), blk = t&7
  const int kc = t >> 3, blk = t & 7;
  const int key = (d >> 1) & 7;
  const float* src = (d < 64) ? (wq + (size_t)d * 2048)
                   : (d < 128) ? (wk + (size_t)(d - 64) * 2048)
                               : (wv + (size_t)(d - 128) * 2048);
  const float* s8 = src + kc * 64 + ((blk ^ key) << 3);
  u16x8 o;
#pragma unroll
  for (int j = 0; j < 8; ++j) o[j] = f2bf(s8[j]);
  *(u16x8*)(Wpk + ((size_t)(kc * 192 + d) << 6) + (blk << 3)) = o;
}

// ============ Fused kernel: qkv -> (per-batch semaphore) -> attn + in-block merge =====
// grid 256 (16b x 16 tile) x 512 thr, LDS 160KB, 1 block/CU, all co-resident.
__global__ __launch_bounds__(512) void fused_qa(
    const float* __restrict__ x,
    const float* __restrict__ bq, const float* __restrict__ bk, const float* __restrict__ bv,
    float* __restrict__ out,
    u16* __restrict__ Qo, u16* __restrict__ Ko, u16* __restrict__ Vt,
    const u16* __restrict__ Wpk, unsigned* __restrict__ sem)
{
  const int bid = blockIdx.x;
  const int tid = threadIdx.x;
  const int lane = tid & 63;
  const int wid  = tid >> 6;
  const int l15 = lane & 15, l4 = lane >> 4;
  const int b  = bid >> 4;
  const int p0 = (bid & 15) * 64;     // ptile for qkv, q-tile for attn

  __shared__ __align__(16) char smem[163840];

  // ---------------- phase 1: fused QKV projection (R10/R11 structure) ----------------
  // lA slot s: smem + s*8192 (4 slots, 32KB). lB slot s: smem + 32768 + s*24576 (96KB).
  {
    const int wm = wid & 1, wn = wid >> 1;
    const int pg = lane & 15;
    const int kb = wid * 4 + (lane >> 4);
    const int k0 = kb * 4;
    const int ww = wid - 4;

    f32x4 acc[2][3];
#pragma unroll
    for (int m = 0; m < 2; ++m)
#pragma unroll
      for (int n = 0; n < 3; ++n) acc[m][n] = (f32x4)(0.0f);

    const float* xb = x + (size_t)b * 2048 * 1024 + p0 + pg * 4;
    float4 SA[8], SB[8];

    auto xload2 = [&](int c, float4 (&S)[8]) {
#pragma unroll
      for (int cc = 0; cc < 2; ++cc) {
        const float* g = xb + (size_t)((c + cc) * 64 + k0) * 1024;
#pragma unroll
        for (int r = 0; r < 4; ++r) S[cc * 4 + r] = *(const float4*)(g + r * 1024);
      }
    };
    auto xstore2 = [&](int c, float4 (&S)[8]) {
#pragma unroll
      for (int cc = 0; cc < 2; ++cc) {
        const int slot = (c + cc) & 3;
#pragma unroll
        for (int col = 0; col < 4; ++col) {
          int p = pg * 4 + col;
          unsigned lo = cvt_pk_bf16(S[cc * 4 + 0][col], S[cc * 4 + 1][col]);
          unsigned hi = cvt_pk_bf16(S[cc * 4 + 2][col], S[cc * 4 + 3][col]);
          int swz = ((kb >> 1) ^ ((p >> 1) & 7)) & 7;
          *(uint2*)(smem + slot * 8192 + p * 128 + (swz << 4) + (kb & 1) * 8)
            = make_uint2(lo, hi);
        }
      }
    };
    auto wissue2 = [&](int c) {
#pragma unroll
      for (int cc = 0; cc < 2; ++cc) {
        const int slot = (c + cc) & 3;
        const u16* g = Wpk + (size_t)(c + cc) * 12288 + lane * 8;
#pragma unroll
        for (int j = 0; j < 6; ++j) {
          int q = ww * 6 + j;
          GLD16(g + q * 512, smem + 32768 + slot * 24576 + q * 1024);
        }
      }
    };
    auto domfma = [&](int slot) {
#pragma unroll
      for (int ks = 0; ks < 2; ++ks) {
        s16x8 af[2], bfv[3];
#pragma unroll
        for (int m = 0; m < 2; ++m) {
          int p = wm * 32 + m * 16 + l15;
          int swz = ((ks * 4 + l4) ^ ((p >> 1) & 7)) & 7;
          af[m] = *(const s16x8*)(smem + slot * 8192 + p * 128 + (swz << 4));
        }
#pragma unroll
        for (int n = 0; n < 3; ++n) {
          int d = wn * 48 + n * 16 + l15;
          int swz = ((ks * 4 + l4) ^ ((d >> 1) & 7)) & 7;
          bfv[n] = *(const s16x8*)(smem + 32768 + slot * 24576 + d * 128 + (swz << 4));
        }
#pragma unroll
        for (int m = 0; m < 2; ++m)
#pragma unroll
          for (int n = 0; n < 3; ++n)
            acc[m][n] = __builtin_amdgcn_mfma_f32_16x16x32_bf16(af[m], bfv[n], acc[m][n], 0, 0, 0);
      }
    };
    auto barrier = [&]() {
      if (wid < 4) asm volatile("s_waitcnt lgkmcnt(0)" ::: "memory");
      else         asm volatile("s_waitcnt vmcnt(0) lgkmcnt(0)" ::: "memory");
      __builtin_amdgcn_sched_barrier(0);
      __builtin_amdgcn_s_barrier();
      __builtin_amdgcn_sched_barrier(0);
    };
    auto step = [&](int t, float4 (&Sl)[8], float4 (&Ss)[8]) {
      if (wid < 4) { if (t < 14) xload2(2 * t + 4, Sl); }
      else         { if (t < 15) wissue2(2 * t + 2); }
      __builtin_amdgcn_s_setprio(1);
      domfma((2 * t) & 3);
      domfma((2 * t + 1) & 3);
      __builtin_amdgcn_s_setprio(0);
      if (wid < 4 && t < 15) xstore2(2 * t + 2, Ss);
      barrier();
    };

    if (wid < 4) { xload2(0, SA); xload2(2, SB); xstore2(0, SA); }
    else         { wissue2(0); }
    barrier();

    for (int tt = 0; tt < 8; ++tt) {
      step(2 * tt,     SA, SB);
      step(2 * tt + 1, SB, SA);
    }

    // epilogue: Q scaled (plain), K swizzled (key=(p>>1)&7), V transposed+swizzled.
#pragma unroll
    for (int n = 0; n < 3; ++n) {
      const int dg = wn * 48 + n * 16 + l15;
      const int wi = dg >> 6, dl = dg & 63;
      const float* bsrc = (wi == 0) ? bq : (wi == 1) ? bk : bv;
      const float bias = bsrc[dl];
#pragma unroll
      for (int m = 0; m < 2; ++m) {
        const int pl = wm * 32 + m * 16 + l4 * 4;
        f32x4 a = acc[m][n];
        if (wi == 0) {
          u16* dst = Qo + ((size_t)b * 1024 + p0 + pl) * 64 + dl;
#pragma unroll
          for (int r = 0; r < 4; ++r) dst[(size_t)r * 64] = f2bf((a[r] + bias) * CEXP);
        } else if (wi == 1) {
#pragma unroll
          for (int r = 0; r < 4; ++r) {
            const int p = p0 + pl + r;
            Ko[((size_t)b * 1024 + p) * 64 + (((dl >> 3) ^ ((p >> 1) & 7)) << 3) + (dl & 7)]
              = f2bf(a[r] + bias);
          }
        } else {
          const int pk0 = p0 + pl;
          ushort4 hh;
          hh.x = f2bf(a[0] + bias); hh.y = f2bf(a[1] + bias);
          hh.z = f2bf(a[2] + bias); hh.w = f2bf(a[3] + bias);
          u16* dst = Vt + ((size_t)b * 64 + dl) * 1024 + (pk0 & ~127)
                   + (((((pk0 >> 3) & 15) ^ ((dl & 7) << 1)) & 15) << 3) + (pk0 & 7);
          *(ushort4*)dst = hh;
        }
      }
    }
  }

  // -------- release: my batch-tile published; acquire: all 16 tiles of my batch ------
  __threadfence();                                   // agent release (L2 writeback)
  if (tid == 0) {
    __hip_atomic_fetch_add(&sem[b], 1u, __ATOMIC_RELEASE, __HIP_MEMORY_SCOPE_AGENT);
    while (__hip_atomic_load(&sem[b], __ATOMIC_ACQUIRE, __HIP_MEMORY_SCOPE_AGENT) < 16u)
      __builtin_amdgcn_s_sleep(2);
  }
  __syncthreads();
  __threadfence();                                   // agent acquire (L2 invalidate)

  // ---------------- phase 2: attention, both KV-halves in-block + LDS merge ----------
  // group h = wid>>2 (waves 0-3: h=0, waves 4-7: h=1), w = wid&3.
  // LDS: group region 64KB each (lK dbuf 2x16K, lV dbuf 2x16K); lP 8x4K at +128K.
  {
    const int h = wid >> 2;
    const int w = wid & 3;
    const int q0 = p0;
    char* gbase = smem + h * 65536;
    char* lPw   = smem + 131072 + wid * 4096;

    s16x8 qa[2];
#pragma unroll
    for (int ks = 0; ks < 2; ++ks)
      qa[ks] = *(const s16x8*)(Qo + ((size_t)b * 1024 + q0 + w * 16 + l15) * 64
                               + ks * 32 + l4 * 8);

    const u16* Kb = Ko + (size_t)b * 65536;
    const u16* Vb = Vt + (size_t)b * 65536;

    float l_run[4];
    f32x4 oacc[4];
#pragma unroll
    for (int r = 0; r < 4; ++r) l_run[r] = 0.f;
#pragma unroll
    for (int n = 0; n < 4; ++n) oacc[n] = (f32x4)(0.0f);

    auto kv_issue = [&](int tile, int buf) {   // 8 GLD16/wave: 4 K + 4 V
      const int pk0 = tile * 128;
#pragma unroll
      for (int jj = 0; jj < 4; ++jj)
        GLD16(Kb + (size_t)(pk0 + w * 32 + jj * 8) * 64 + lane * 8,
              gbase + buf * 16384 + (w * 4 + jj) * 1024);
#pragma unroll
      for (int jj = 0; jj < 4; ++jj)
        GLD16(Vb + (size_t)(w * 16 + jj * 4 + (lane >> 4)) * 1024 + pk0 + (lane & 15) * 8,
              gbase + 32768 + buf * 16384 + (w * 4 + jj) * 1024);
    };

    auto compute = [&](int buf) {
      const char* kB = gbase + buf * 16384;
      const char* vB = gbase + 32768 + buf * 16384;
      f32x4 sacc[8];
#pragma unroll
      for (int n = 0; n < 8; ++n) sacc[n] = (f32x4)(0.0f);
      __builtin_amdgcn_s_setprio(1);
#pragma unroll
      for (int ks = 0; ks < 2; ++ks) {
#pragma unroll
        for (int n = 0; n < 8; ++n) {
          int row = n * 16 + l15;
          s16x8 kv = *(const s16x8*)(kB + row * 128 +
                       ((((ks * 4 + l4) ^ ((row >> 1) & 7)) & 7) << 4));
          sacc[n] = __builtin_amdgcn_mfma_f32_16x16x32_bf16(qa[ks], kv, sacc[n], 0, 0, 0);
        }
      }
      __builtin_amdgcn_s_setprio(0);

#pragma unroll
      for (int r = 0; r < 4; ++r) {
        const int prow = l4 * 4 + r;
        const int key = (prow & 7) << 1;
        float pv[8];
        float psum = 0.f;
#pragma unroll
        for (int n = 0; n < 8; ++n) { pv[n] = exp2f(sacc[n][r]); psum += pv[n]; }
#pragma unroll
        for (int n = 0; n < 8; n += 2) {
          unsigned pk = cvt_pk_bf16(pv[n], pv[n + 1]);
          int blk0 = ((n * 2 + (l15 >> 3)) ^ key) & 15;
          int blk1 = (((n + 1) * 2 + (l15 >> 3)) ^ key) & 15;
          *(u16*)(lPw + prow * 256 + blk0 * 16 + (l15 & 7) * 2) = (u16)pk;
          *(u16*)(lPw + prow * 256 + blk1 * 16 + (l15 & 7) * 2) = (u16)(pk >> 16);
        }
        psum += __shfl_xor(psum, 1);
        psum += __shfl_xor(psum, 2);
        psum += __shfl_xor(psum, 4);
        psum += __shfl_xor(psum, 8);
        l_run[r] += psum;
      }

      __builtin_amdgcn_s_setprio(1);
#pragma unroll
      for (int ks = 0; ks < 4; ++ks) {
        s16x8 pfr = *(const s16x8*)(lPw + l15 * 256 +
                      ((((ks * 4 + l4) ^ ((l15 & 7) << 1)) & 15) << 4));
#pragma unroll
        for (int n = 0; n < 4; ++n) {
          int row = n * 16 + l15;
          s16x8 vv = *(const s16x8*)(vB + row * 256 +
                       ((((ks * 4 + l4) ^ ((row & 7) << 1)) & 15) << 4));
          oacc[n] = __builtin_amdgcn_mfma_f32_16x16x32_bf16(pfr, vv, oacc[n], 0, 0, 0);
        }
      }
      __builtin_amdgcn_s_setprio(0);
    };

    const int t0 = h * 4;
    kv_issue(t0, 0);
    kv_issue(t0 + 1, 1);
    asm volatile("s_waitcnt vmcnt(8)" ::: "memory");
    __builtin_amdgcn_sched_barrier(0);
    __builtin_amdgcn_s_barrier();
    __builtin_amdgcn_sched_barrier(0);

    for (int ic = 0; ic < 4; ++ic) {
      compute(ic & 1);
      if (ic < 3) {
        __builtin_amdgcn_sched_barrier(0);
        __builtin_amdgcn_s_barrier();
        __builtin_amdgcn_sched_barrier(0);
        if (ic + 2 < 4) {
          kv_issue(t0 + ic + 2, ic & 1);
          asm volatile("s_waitcnt vmcnt(8)" ::: "memory");
        } else {
          asm volatile("s_waitcnt vmcnt(0)" ::: "memory");
        }
        __builtin_amdgcn_sched_barrier(0);
        __builtin_amdgcn_s_barrier();
        __builtin_amdgcn_sched_barrier(0);
      }
    }

    // in-block merge of the two halves through LDS (reuses group-0 K region)
    __syncthreads();
    if (h == 1) {
      float* mrg = (float*)smem + (tid - 256) * 20;
#pragma unroll
      for (int n = 0; n < 4; ++n) *(f32x4*)(mrg + n * 4) = oacc[n];
#pragma unroll
      for (int r = 0; r < 4; ++r) mrg[16 + r] = l_run[r];
    }
    __syncthreads();
    if (h == 0) {
      const float* mrg = (const float*)smem + tid * 20;
      float lr[4];
#pragma unroll
      for (int r = 0; r < 4; ++r) lr[r] = l_run[r] + mrg[16 + r];
#pragma unroll
      for (int n = 0; n < 4; ++n) {
        f32x4 o1 = *(const f32x4*)(mrg + n * 4);
        float4 o;
        o.x = (oacc[n][0] + o1[0]) / lr[0];
        o.y = (oacc[n][1] + o1[1]) / lr[1];
        o.z = (oacc[n][2] + o1[2]) / lr[2];
        o.w = (oacc[n][3] + o1[3]) / lr[3];
        *(float4*)(out + ((size_t)b * 64 + n * 16 + l15) * 1024 + q0 + w * 16 + l4 * 4) = o;
      }
    }
  }
}

extern "C" void kernel_launch(void* const* d_in, const int* in_sizes, int n_in,
                              void* d_out, int out_size, void* d_ws, size_t ws_size,
                              hipStream_t stream) {
  const float* x  = (const float*)d_in[0];
  const float* wq = (const float*)d_in[1];
  const float* bq = (const float*)d_in[2];
  const float* wk = (const float*)d_in[3];
  const float* bk = (const float*)d_in[4];
  const float* wv = (const float*)d_in[5];
  const float* bv = (const float*)d_in[6];
  float* out = (float*)d_out;

  u16* Qo  = (u16*)d_ws;                              // [16][1024][64] bf16 (scaled)
  u16* Ko  = Qo + (size_t)16 * 1024 * 64;             // [16][1024][64] bf16, swizzled
  u16* Vt  = Ko + (size_t)16 * 1024 * 64;             // [16][64][1024] bf16, swizzled
  u16* Wpk = Vt + (size_t)16 * 1024 * 64;             // [32][192][64] bf16 prepacked
  unsigned* sem = (unsigned*)(Wpk + (size_t)32 * 192 * 64);   // [16] batch counters

  prepack_w<<<192, 256, 0, stream>>>(wq, wk, wv, Wpk, sem);
  fused_qa<<<256, 512, 0, stream>>>(x, bq, bk, bv, out, Qo, Ko, Vt, Wpk, sem);
}

// Round 14
// 55.396 us; speedup vs baseline: 2.9070x; 2.9070x over previous
//
#include <hip/hip_runtime.h>

typedef float f32x4 __attribute__((ext_vector_type(4)));
typedef short s16x8 __attribute__((ext_vector_type(8)));
typedef unsigned u32x4 __attribute__((ext_vector_type(4)));
typedef unsigned short u16;
typedef unsigned short u16x8 __attribute__((ext_vector_type(8)));

__device__ __forceinline__ u16 f2bf(float f) {
  unsigned u = __builtin_bit_cast(unsigned, f);
  u += 0x7fffu + ((u >> 16) & 1u);   // RNE
  return (u16)(u >> 16);
}

__device__ __forceinline__ unsigned cvt_pk_bf16(float a, float b) {
  unsigned r;
  asm("v_cvt_pk_bf16_f32 %0, %1, %2" : "=v"(r) : "v"(a), "v"(b));
  return r;   // lo = bf16(a), hi = bf16(b), RNE
}

#define AS1 __attribute__((address_space(1)))
#define AS3 __attribute__((address_space(3)))
#define GLD16(g, l) __builtin_amdgcn_global_load_lds((const AS1 unsigned int*)(g), (AS3 unsigned int*)(l), 16, 0, 0)

// Q is pre-scaled by log2(e)/64 at projection so attn uses exp2 directly.
#define CEXP 0.0225421101f

// ---------------- Kernel 0: prepack W -> bf16, chunk-major, swizzled ----------------
__global__ __launch_bounds__(256) void prepack_w(
    const float* __restrict__ wq, const float* __restrict__ wk, const float* __restrict__ wv,
    u16* __restrict__ Wpk)
{
  const int d = blockIdx.x;          // 0..191
  const int t = threadIdx.x;         // kc = t>>3 (0..31), blk = t&7
  const int kc = t >> 3, blk = t & 7;
  const int key = (d >> 1) & 7;
  const float* src = (d < 64) ? (wq + (size_t)d * 2048)
                   : (d < 128) ? (wk + (size_t)(d - 64) * 2048)
                               : (wv + (size_t)(d - 128) * 2048);
  const float* s8 = src + kc * 64 + ((blk ^ key) << 3);
  u16x8 o;
#pragma unroll
  for (int j = 0; j < 8; ++j) o[j] = f2bf(s8[j]);
  *(u16x8*)(Wpk + ((size_t)(kc * 192 + d) << 6) + (blk << 3)) = o;
}

// ---------------- Kernel 1: fused QKV projection (R10 structure) ----------------
// grid 256 (16 b x 16 ptile of 64), block 512 (8 waves).
// Epilogue: Q scaled by CEXP; K stored PRE-PERMUTED (pk bits 2->3->4->2 rotation, for
// in-register-P attention) and PRE-SWIZZLED; V transposed + pre-swizzled.
__global__ __launch_bounds__(512) void qkv_proj(
    const float* __restrict__ x, const u16* __restrict__ Wpk,
    const float* __restrict__ bq, const float* __restrict__ bk, const float* __restrict__ bv,
    u16* __restrict__ Qo, u16* __restrict__ Ko, u16* __restrict__ Vt)
{
  const int b   = blockIdx.x >> 4;
  const int p0  = (blockIdx.x & 15) * 64;
  const int tid = threadIdx.x;
  const int lane = tid & 63;
  const int wid  = tid >> 6;
  const int l15 = lane & 15, l4 = lane >> 4;
  const int wm = wid & 1, wn = wid >> 1;

  __shared__ __align__(16) u16 lA[4][64 * 64];    // 32 KiB
  __shared__ __align__(16) u16 lB[4][192 * 64];   // 96 KiB

  const int pg = lane & 15;
  const int kb = wid * 4 + (lane >> 4);   // 0..15 (x-waves)
  const int k0 = kb * 4;
  const int ww = wid - 4;                 // 0..3 (W-waves)

  f32x4 acc[2][3];
#pragma unroll
  for (int m = 0; m < 2; ++m)
#pragma unroll
    for (int n = 0; n < 3; ++n) acc[m][n] = (f32x4)(0.0f);

  const float* xb = x + (size_t)b * 2048 * 1024 + p0 + pg * 4;
  float4 SA[8], SB[8];

  auto xload2 = [&](int c, float4 (&S)[8]) {
#pragma unroll
    for (int cc = 0; cc < 2; ++cc) {
      const float* g = xb + (size_t)((c + cc) * 64 + k0) * 1024;
#pragma unroll
      for (int r = 0; r < 4; ++r) S[cc * 4 + r] = *(const float4*)(g + r * 1024);
    }
  };
  auto xstore2 = [&](int c, float4 (&S)[8]) {
#pragma unroll
    for (int cc = 0; cc < 2; ++cc) {
      const int slot = (c + cc) & 3;
#pragma unroll
      for (int col = 0; col < 4; ++col) {
        int p = pg * 4 + col;
        unsigned lo = cvt_pk_bf16(S[cc * 4 + 0][col], S[cc * 4 + 1][col]);
        unsigned hi = cvt_pk_bf16(S[cc * 4 + 2][col], S[cc * 4 + 3][col]);
        int swz = ((kb >> 1) ^ ((p >> 1) & 7)) & 7;
        char* dst = (char*)&lA[0][0] + slot * 8192 + p * 128 + (swz << 4) + (kb & 1) * 8;
        *(uint2*)dst = make_uint2(lo, hi);
      }
    }
  };
  auto wissue2 = [&](int c) {
#pragma unroll
    for (int cc = 0; cc < 2; ++cc) {
      const int slot = (c + cc) & 3;
      const u16* g = Wpk + (size_t)(c + cc) * 12288 + lane * 8;
#pragma unroll
      for (int j = 0; j < 6; ++j) {
        int q = ww * 6 + j;
        GLD16(g + q * 512, &lB[0][0] + slot * 12288 + q * 512);
      }
    }
  };
  auto domfma = [&](int slot) {
#pragma unroll
    for (int ks = 0; ks < 2; ++ks) {
      s16x8 af[2], bfv[3];
#pragma unroll
      for (int m = 0; m < 2; ++m) {
        int p = wm * 32 + m * 16 + l15;
        int swz = ((ks * 4 + l4) ^ ((p >> 1) & 7)) & 7;
        af[m] = *(const s16x8*)((const char*)&lA[0][0] + slot * 8192 + p * 128 + (swz << 4));
      }
#pragma unroll
      for (int n = 0; n < 3; ++n) {
        int d = wn * 48 + n * 16 + l15;
        int swz = ((ks * 4 + l4) ^ ((d >> 1) & 7)) & 7;
        bfv[n] = *(const s16x8*)((const char*)&lB[0][0] + slot * 24576 + d * 128 + (swz << 4));
      }
#pragma unroll
      for (int m = 0; m < 2; ++m)
#pragma unroll
        for (int n = 0; n < 3; ++n)
          acc[m][n] = __builtin_amdgcn_mfma_f32_16x16x32_bf16(af[m], bfv[n], acc[m][n], 0, 0, 0);
    }
  };
  auto barrier = [&]() {
    if (wid < 4) asm volatile("s_waitcnt lgkmcnt(0)" ::: "memory");
    else         asm volatile("s_waitcnt vmcnt(0) lgkmcnt(0)" ::: "memory");
    __builtin_amdgcn_sched_barrier(0);
    __builtin_amdgcn_s_barrier();
    __builtin_amdgcn_sched_barrier(0);
  };
  auto step = [&](int t, float4 (&Sl)[8], float4 (&Ss)[8]) {
    if (wid < 4) { if (t < 14) xload2(2 * t + 4, Sl); }
    else         { if (t < 15) wissue2(2 * t + 2); }
    __builtin_amdgcn_s_setprio(1);
    domfma((2 * t) & 3);
    domfma((2 * t + 1) & 3);
    __builtin_amdgcn_s_setprio(0);
    if (wid < 4 && t < 15) xstore2(2 * t + 2, Ss);
    barrier();
  };

  // prologue: x(0,1)->SA, x(2,3)->SB, store SA; W(0,1) issued+waited
  if (wid < 4) { xload2(0, SA); xload2(2, SB); xstore2(0, SA); }
  else         { wissue2(0); }
  barrier();

  for (int tt = 0; tt < 8; ++tt) {
    step(2 * tt,     SA, SB);
    step(2 * tt + 1, SB, SA);
  }

  // epilogue: bias + store.
  // Q: [b][p][64], scaled by CEXP.
  // K: row index permuted p->p2 (rotate bits 2<-3<-4<-2), then d-block swizzle key=(p2>>1)&7.
  // V: [b][64][1024] transposed, pk-block-swizzled (key=(d&7)<<1).
#pragma unroll
  for (int n = 0; n < 3; ++n) {
    const int dg = wn * 48 + n * 16 + l15;
    const int wi = dg >> 6, dl = dg & 63;
    const float* bsrc = (wi == 0) ? bq : (wi == 1) ? bk : bv;
    const float bias = bsrc[dl];
#pragma unroll
    for (int m = 0; m < 2; ++m) {
      const int pl = wm * 32 + m * 16 + l4 * 4;
      f32x4 a = acc[m][n];
      if (wi == 0) {
        u16* dst = Qo + ((size_t)b * 1024 + p0 + pl) * 64 + dl;
#pragma unroll
        for (int r = 0; r < 4; ++r) dst[(size_t)r * 64] = f2bf((a[r] + bias) * CEXP);
      } else if (wi == 1) {
#pragma unroll
        for (int r = 0; r < 4; ++r) {
          const int p = p0 + pl + r;
          const int p2 = (p & ~28) | ((p & 8) >> 1) | ((p & 16) >> 1) | ((p & 4) << 2);
          Ko[((size_t)b * 1024 + p2) * 64 + (((dl >> 3) ^ ((p2 >> 1) & 7)) << 3) + (dl & 7)]
            = f2bf(a[r] + bias);
        }
      } else {
        const int pk0 = p0 + pl;
        ushort4 hh;
        hh.x = f2bf(a[0] + bias); hh.y = f2bf(a[1] + bias);
        hh.z = f2bf(a[2] + bias); hh.w = f2bf(a[3] + bias);
        u16* dst = Vt + ((size_t)b * 64 + dl) * 1024 + (pk0 & ~127)
                 + (((((pk0 >> 3) & 15) ^ ((dl & 7) << 1)) & 15) << 3) + (pk0 & 7);
        *(ushort4*)dst = hh;
      }
    }
  }
}

// ---------------- Kernel 2: flash attention (swapped QK^T, in-register P) ----------
// grid 512 = b(16) x qtile(16) x half(2); block 256 (4 waves x 16 q-rows).
// mfma(K,Q) -> lane holds P[pk][q=l15]; K rows pre-permuted so lane's 32 P-values are
// exactly its PV A-fragment (pk = 32ks+8*l4+j) -> zero cross-lane exchange, no P LDS.
__global__ __launch_bounds__(256) void attn_kernel(
    const u16* __restrict__ Qg, const u16* __restrict__ Kg,
    const u16* __restrict__ Vg, float* __restrict__ Po, float* __restrict__ lp)
{
  const int bid = blockIdx.x;
  const int b  = bid >> 5;
  const int qt = (bid >> 1) & 15;
  const int h  = bid & 1;
  const int q0 = qt * 64;
  const int tid = threadIdx.x;
  const int lane = tid & 63;
  const int w = tid >> 6;
  const int l15 = lane & 15, l4 = lane >> 4;
  const int qb = q0 + w * 16;

  __shared__ __align__(16) u16 lK[2][128 * 64];   // swz: blk^=(row>>1)&7 (content from Ko)
  __shared__ __align__(16) u16 lV[2][64 * 128];   // swz: blk^=(row&7)<<1 (content from Vt)

  s16x8 qa[2];
#pragma unroll
  for (int ks = 0; ks < 2; ++ks)
    qa[ks] = *(const s16x8*)(Qg + ((size_t)b * 1024 + qb + l15) * 64 + ks * 32 + l4 * 8);

  const u16* Kb = Kg + (size_t)b * 65536;
  const u16* Vb = Vg + (size_t)b * 65536;

  float l_run = 0.f;
  f32x4 oacc[4];
#pragma unroll
  for (int n = 0; n < 4; ++n) oacc[n] = (f32x4)(0.0f);

  auto kv_issue = [&](int tile, int buf) {   // 8 GLD16/wave: 4 K + 4 V
    const int pk0 = tile * 128;
#pragma unroll
    for (int jj = 0; jj < 4; ++jj)
      GLD16(Kb + (size_t)(pk0 + w * 32 + jj * 8) * 64 + lane * 8,
            (char*)&lK[buf][0] + (w * 4 + jj) * 1024);
#pragma unroll
    for (int jj = 0; jj < 4; ++jj)
      GLD16(Vb + (size_t)(w * 16 + jj * 4 + (lane >> 4)) * 1024 + pk0 + (lane & 15) * 8,
            (char*)&lV[buf][0] + (w * 4 + jj) * 1024);
  };

  auto compute = [&](int buf) {
    f32x4 sacc[8];
#pragma unroll
    for (int n = 0; n < 8; ++n) sacc[n] = (f32x4)(0.0f);
    __builtin_amdgcn_s_setprio(1);
#pragma unroll
    for (int ks = 0; ks < 2; ++ks) {
#pragma unroll
      for (int n = 0; n < 8; ++n) {
        int row = n * 16 + l15;
        s16x8 kv = *(const s16x8*)(&lK[buf][0] + row * 64 +
                     (((ks * 4 + l4) ^ ((row >> 1) & 7)) << 3));
        sacc[n] = __builtin_amdgcn_mfma_f32_16x16x32_bf16(kv, qa[ks], sacc[n], 0, 0, 0);
      }
    }
    __builtin_amdgcn_s_setprio(0);

    // in-register softmax: lane holds P[pk = 32*(n>>1) + 8*l4 + 4*(n&1) + r][q=l15]
    unsigned c[8][2];
    float psum = 0.f;
#pragma unroll
    for (int n = 0; n < 8; ++n) {
      float e0 = exp2f(sacc[n][0]);
      float e1 = exp2f(sacc[n][1]);
      float e2 = exp2f(sacc[n][2]);
      float e3 = exp2f(sacc[n][3]);
      psum += (e0 + e1) + (e2 + e3);
      c[n][0] = cvt_pk_bf16(e0, e1);
      c[n][1] = cvt_pk_bf16(e2, e3);
    }
    psum += __shfl_xor(psum, 16);
    psum += __shfl_xor(psum, 32);
    l_run += psum;

    __builtin_amdgcn_s_setprio(1);
#pragma unroll
    for (int ks = 0; ks < 4; ++ks) {
      u32x4 t;
      t[0] = c[2 * ks][0];
      t[1] = c[2 * ks][1];
      t[2] = c[2 * ks + 1][0];
      t[3] = c[2 * ks + 1][1];
      s16x8 pfr = __builtin_bit_cast(s16x8, t);
#pragma unroll
      for (int n = 0; n < 4; ++n) {
        int row = n * 16 + l15;
        s16x8 vv = *(const s16x8*)(&lV[buf][0] + row * 128 +
                     (((ks * 4 + l4) ^ ((row & 7) << 1)) << 3));
        oacc[n] = __builtin_amdgcn_mfma_f32_16x16x32_bf16(pfr, vv, oacc[n], 0, 0, 0);
      }
    }
    __builtin_amdgcn_s_setprio(0);
  };

  const int t0 = h * 4;
  // prologue: tiles t0, t0+1 issued; wait tile t0 (8 younger outstanding allowed)
  kv_issue(t0, 0);
  kv_issue(t0 + 1, 1);
  asm volatile("s_waitcnt vmcnt(8)" ::: "memory");
  __builtin_amdgcn_sched_barrier(0);
  __builtin_amdgcn_s_barrier();
  __builtin_amdgcn_sched_barrier(0);

  for (int ic = 0; ic < 4; ++ic) {
    compute(ic & 1);
    if (ic < 3) {
      __builtin_amdgcn_sched_barrier(0);
      __builtin_amdgcn_s_barrier();        // all waves done reading buf ic&1
      __builtin_amdgcn_sched_barrier(0);
      if (ic + 2 < 4) {
        kv_issue(t0 + ic + 2, ic & 1);
        asm volatile("s_waitcnt vmcnt(8)" ::: "memory");   // tile ic+1 complete
      } else {
        asm volatile("s_waitcnt vmcnt(0)" ::: "memory");   // tile 3 complete
      }
      __builtin_amdgcn_sched_barrier(0);
      __builtin_amdgcn_s_barrier();        // tile ic+1 visible to all waves
      __builtin_amdgcn_sched_barrier(0);
    }
  }

  // redistribute l: lane (l15,l4) needs l for q = l4*4+r, held by lane (l4*4+r)
  float lr[4];
#pragma unroll
  for (int r = 0; r < 4; ++r) lr[r] = __shfl(l_run, l4 * 4 + r);

  // partial store: Po[h][b][d][p], lp[h][b][q]
#pragma unroll
  for (int n = 0; n < 4; ++n) {
    const int d = n * 16 + l15;
    float4 o;
    o.x = oacc[n][0]; o.y = oacc[n][1]; o.z = oacc[n][2]; o.w = oacc[n][3];
    *(float4*)(Po + (((size_t)h * 16 + b) * 64 + d) * 1024 + q0 + w * 16 + l4 * 4) = o;
  }
  if (l15 == 0) {
#pragma unroll
    for (int r = 0; r < 4; ++r)
      lp[((size_t)h * 16 + b) * 1024 + qb + l4 * 4 + r] = lr[r];
  }
}

// ---------------- Kernel 3: merge halves ----------------
__global__ __launch_bounds__(256) void attn_merge(
    const float* __restrict__ Po, const float* __restrict__ lp, float* __restrict__ out)
{
  const int i = (blockIdx.x * 256 + threadIdx.x) * 4;
  float4 a = *(const float4*)(Po + i);
  float4 c = *(const float4*)(Po + 1048576 + i);
  const int b = i >> 16;
  const int p = i & 1023;
  const float* l0 = lp + b * 1024 + p;
  const float* l1 = lp + 16384 + b * 1024 + p;
  float4 o;
  o.x = (a.x + c.x) / (l0[0] + l1[0]);
  o.y = (a.y + c.y) / (l0[1] + l1[1]);
  o.z = (a.z + c.z) / (l0[2] + l1[2]);
  o.w = (a.w + c.w) / (l0[3] + l1[3]);
  *(float4*)(out + i) = o;
}

extern "C" void kernel_launch(void* const* d_in, const int* in_sizes, int n_in,
                              void* d_out, int out_size, void* d_ws, size_t ws_size,
                              hipStream_t stream) {
  const float* x  = (const float*)d_in[0];
  const float* wq = (const float*)d_in[1];
  const float* bq = (const float*)d_in[2];
  const float* wk = (const float*)d_in[3];
  const float* bk = (const float*)d_in[4];
  const float* wv = (const float*)d_in[5];
  const float* bv = (const float*)d_in[6];
  float* out = (float*)d_out;

  u16* Qo  = (u16*)d_ws;                              // [16][1024][64] bf16 (scaled)
  u16* Ko  = Qo + (size_t)16 * 1024 * 64;             // [16][1024][64] bf16, permuted+swizzled
  u16* Vt  = Ko + (size_t)16 * 1024 * 64;             // [16][64][1024] bf16, swizzled
  u16* Wpk = Vt + (size_t)16 * 1024 * 64;             // [32][192][64] bf16 prepacked
  float* Po = (float*)(Wpk + (size_t)32 * 192 * 64);  // [2][16][64][1024] f32 partial O
  float* lpart = Po + (size_t)2 * 16 * 64 * 1024;     // [2][16][1024] f32 partial l

  prepack_w<<<192, 256, 0, stream>>>(wq, wk, wv, Wpk);
  qkv_proj<<<256, 512, 0, stream>>>(x, Wpk, bq, bk, bv, Qo, Ko, Vt);
  attn_kernel<<<512, 256, 0, stream>>>(Qo, Ko, Vt, Po, lpart);
  attn_merge<<<1024, 256, 0, stream>>>(Po, lpart, out);
}

// Round 15
// 52.633 us; speedup vs baseline: 3.0597x; 1.0525x over previous
//
#include <hip/hip_runtime.h>

typedef float f32x4 __attribute__((ext_vector_type(4)));
typedef short s16x8 __attribute__((ext_vector_type(8)));
typedef unsigned u32x4 __attribute__((ext_vector_type(4)));
typedef unsigned short u16;
typedef unsigned short u16x8 __attribute__((ext_vector_type(8)));

__device__ __forceinline__ u16 f2bf(float f) {
  unsigned u = __builtin_bit_cast(unsigned, f);
  u += 0x7fffu + ((u >> 16) & 1u);   // RNE
  return (u16)(u >> 16);
}

__device__ __forceinline__ unsigned cvt_pk_bf16(float a, float b) {
  unsigned r;
  asm("v_cvt_pk_bf16_f32 %0, %1, %2" : "=v"(r) : "v"(a), "v"(b));
  return r;   // lo = bf16(a), hi = bf16(b), RNE
}

#define AS1 __attribute__((address_space(1)))
#define AS3 __attribute__((address_space(3)))
#define GLD16(g, l) __builtin_amdgcn_global_load_lds((const AS1 unsigned int*)(g), (AS3 unsigned int*)(l), 16, 0, 0)

// Q is pre-scaled by log2(e)/64 at projection so attn uses exp2 directly.
#define CEXP 0.0225421101f

// ---------------- Kernel 0: prepack W -> bf16, chunk-major, swizzled ----------------
__global__ __launch_bounds__(256) void prepack_w(
    const float* __restrict__ wq, const float* __restrict__ wk, const float* __restrict__ wv,
    u16* __restrict__ Wpk)
{
  const int d = blockIdx.x;          // 0..191
  const int t = threadIdx.x;         // kc = t>>3 (0..31), blk = t&7
  const int kc = t >> 3, blk = t & 7;
  const int key = (d >> 1) & 7;
  const float* src = (d < 64) ? (wq + (size_t)d * 2048)
                   : (d < 128) ? (wk + (size_t)(d - 64) * 2048)
                               : (wv + (size_t)(d - 128) * 2048);
  const float* s8 = src + kc * 64 + ((blk ^ key) << 3);
  u16x8 o;
#pragma unroll
  for (int j = 0; j < 8; ++j) o[j] = f2bf(s8[j]);
  *(u16x8*)(Wpk + ((size_t)(kc * 192 + d) << 6) + (blk << 3)) = o;
}

// ---------------- Kernel 1: fused QKV projection (R14, unchanged) ----------------
// grid 256 (16 b x 16 ptile of 64), block 512 (8 waves).
// Epilogue: Q scaled by CEXP; K stored PRE-PERMUTED (pk bits 2->3->4->2 rotation, for
// in-register-P attention) and PRE-SWIZZLED; V transposed + pre-swizzled.
__global__ __launch_bounds__(512) void qkv_proj(
    const float* __restrict__ x, const u16* __restrict__ Wpk,
    const float* __restrict__ bq, const float* __restrict__ bk, const float* __restrict__ bv,
    u16* __restrict__ Qo, u16* __restrict__ Ko, u16* __restrict__ Vt)
{
  const int b   = blockIdx.x >> 4;
  const int p0  = (blockIdx.x & 15) * 64;
  const int tid = threadIdx.x;
  const int lane = tid & 63;
  const int wid  = tid >> 6;
  const int l15 = lane & 15, l4 = lane >> 4;
  const int wm = wid & 1, wn = wid >> 1;

  __shared__ __align__(16) u16 lA[4][64 * 64];    // 32 KiB
  __shared__ __align__(16) u16 lB[4][192 * 64];   // 96 KiB

  const int pg = lane & 15;
  const int kb = wid * 4 + (lane >> 4);   // 0..15 (x-waves)
  const int k0 = kb * 4;
  const int ww = wid - 4;                 // 0..3 (W-waves)

  f32x4 acc[2][3];
#pragma unroll
  for (int m = 0; m < 2; ++m)
#pragma unroll
    for (int n = 0; n < 3; ++n) acc[m][n] = (f32x4)(0.0f);

  const float* xb = x + (size_t)b * 2048 * 1024 + p0 + pg * 4;
  float4 SA[8], SB[8];

  auto xload2 = [&](int c, float4 (&S)[8]) {
#pragma unroll
    for (int cc = 0; cc < 2; ++cc) {
      const float* g = xb + (size_t)((c + cc) * 64 + k0) * 1024;
#pragma unroll
      for (int r = 0; r < 4; ++r) S[cc * 4 + r] = *(const float4*)(g + r * 1024);
    }
  };
  auto xstore2 = [&](int c, float4 (&S)[8]) {
#pragma unroll
    for (int cc = 0; cc < 2; ++cc) {
      const int slot = (c + cc) & 3;
#pragma unroll
      for (int col = 0; col < 4; ++col) {
        int p = pg * 4 + col;
        unsigned lo = cvt_pk_bf16(S[cc * 4 + 0][col], S[cc * 4 + 1][col]);
        unsigned hi = cvt_pk_bf16(S[cc * 4 + 2][col], S[cc * 4 + 3][col]);
        int swz = ((kb >> 1) ^ ((p >> 1) & 7)) & 7;
        char* dst = (char*)&lA[0][0] + slot * 8192 + p * 128 + (swz << 4) + (kb & 1) * 8;
        *(uint2*)dst = make_uint2(lo, hi);
      }
    }
  };
  auto wissue2 = [&](int c) {
#pragma unroll
    for (int cc = 0; cc < 2; ++cc) {
      const int slot = (c + cc) & 3;
      const u16* g = Wpk + (size_t)(c + cc) * 12288 + lane * 8;
#pragma unroll
      for (int j = 0; j < 6; ++j) {
        int q = ww * 6 + j;
        GLD16(g + q * 512, &lB[0][0] + slot * 12288 + q * 512);
      }
    }
  };
  auto domfma = [&](int slot) {
#pragma unroll
    for (int ks = 0; ks < 2; ++ks) {
      s16x8 af[2], bfv[3];
#pragma unroll
      for (int m = 0; m < 2; ++m) {
        int p = wm * 32 + m * 16 + l15;
        int swz = ((ks * 4 + l4) ^ ((p >> 1) & 7)) & 7;
        af[m] = *(const s16x8*)((const char*)&lA[0][0] + slot * 8192 + p * 128 + (swz << 4));
      }
#pragma unroll
      for (int n = 0; n < 3; ++n) {
        int d = wn * 48 + n * 16 + l15;
        int swz = ((ks * 4 + l4) ^ ((d >> 1) & 7)) & 7;
        bfv[n] = *(const s16x8*)((const char*)&lB[0][0] + slot * 24576 + d * 128 + (swz << 4));
      }
#pragma unroll
      for (int m = 0; m < 2; ++m)
#pragma unroll
        for (int n = 0; n < 3; ++n)
          acc[m][n] = __builtin_amdgcn_mfma_f32_16x16x32_bf16(af[m], bfv[n], acc[m][n], 0, 0, 0);
    }
  };
  auto barrier = [&]() {
    if (wid < 4) asm volatile("s_waitcnt lgkmcnt(0)" ::: "memory");
    else         asm volatile("s_waitcnt vmcnt(0) lgkmcnt(0)" ::: "memory");
    __builtin_amdgcn_sched_barrier(0);
    __builtin_amdgcn_s_barrier();
    __builtin_amdgcn_sched_barrier(0);
  };
  auto step = [&](int t, float4 (&Sl)[8], float4 (&Ss)[8]) {
    if (wid < 4) { if (t < 14) xload2(2 * t + 4, Sl); }
    else         { if (t < 15) wissue2(2 * t + 2); }
    __builtin_amdgcn_s_setprio(1);
    domfma((2 * t) & 3);
    domfma((2 * t + 1) & 3);
    __builtin_amdgcn_s_setprio(0);
    if (wid < 4 && t < 15) xstore2(2 * t + 2, Ss);
    barrier();
  };

  // prologue: x(0,1)->SA, x(2,3)->SB, store SA; W(0,1) issued+waited
  if (wid < 4) { xload2(0, SA); xload2(2, SB); xstore2(0, SA); }
  else         { wissue2(0); }
  barrier();

  for (int tt = 0; tt < 8; ++tt) {
    step(2 * tt,     SA, SB);
    step(2 * tt + 1, SB, SA);
  }

  // epilogue: bias + store.
  // Q: [b][p][64], scaled by CEXP.
  // K: row index permuted p->p2 (rotate bits 2<-3<-4<-2), then d-block swizzle key=(p2>>1)&7.
  // V: [b][64][1024] transposed, pk-block-swizzled (key=(d&7)<<1).
#pragma unroll
  for (int n = 0; n < 3; ++n) {
    const int dg = wn * 48 + n * 16 + l15;
    const int wi = dg >> 6, dl = dg & 63;
    const float* bsrc = (wi == 0) ? bq : (wi == 1) ? bk : bv;
    const float bias = bsrc[dl];
#pragma unroll
    for (int m = 0; m < 2; ++m) {
      const int pl = wm * 32 + m * 16 + l4 * 4;
      f32x4 a = acc[m][n];
      if (wi == 0) {
        u16* dst = Qo + ((size_t)b * 1024 + p0 + pl) * 64 + dl;
#pragma unroll
        for (int r = 0; r < 4; ++r) dst[(size_t)r * 64] = f2bf((a[r] + bias) * CEXP);
      } else if (wi == 1) {
#pragma unroll
        for (int r = 0; r < 4; ++r) {
          const int p = p0 + pl + r;
          const int p2 = (p & ~28) | ((p & 8) >> 1) | ((p & 16) >> 1) | ((p & 4) << 2);
          Ko[((size_t)b * 1024 + p2) * 64 + (((dl >> 3) ^ ((p2 >> 1) & 7)) << 3) + (dl & 7)]
            = f2bf(a[r] + bias);
        }
      } else {
        const int pk0 = p0 + pl;
        ushort4 hh;
        hh.x = f2bf(a[0] + bias); hh.y = f2bf(a[1] + bias);
        hh.z = f2bf(a[2] + bias); hh.w = f2bf(a[3] + bias);
        u16* dst = Vt + ((size_t)b * 64 + dl) * 1024 + (pk0 & ~127)
                 + (((((pk0 >> 3) & 15) ^ ((dl & 7) << 1)) & 15) << 3) + (pk0 & 7);
        *(ushort4*)dst = hh;
      }
    }
  }
}

// ---------------- Kernel 2: flash attention, both halves in-block + LDS merge -------
// grid 256 = b(16) x qtile(16); block 512 (8 waves). Waves 0-3: KV half 0; 4-7: half 1
// (symmetric schedule -> block barriers safe, structure validated in R11 phase 2).
// Per group: R14's swapped-QK^T in-register-P body. Final: in-block merge via LDS,
// direct out write (no merge kernel, no Po/lp traffic).
__global__ __launch_bounds__(512) void attn_kernel(
    const u16* __restrict__ Qg, const u16* __restrict__ Kg,
    const u16* __restrict__ Vg, float* __restrict__ out)
{
  const int bid = blockIdx.x;
  const int b  = bid >> 4;
  const int qt = bid & 15;
  const int q0 = qt * 64;
  const int tid = threadIdx.x;
  const int lane = tid & 63;
  const int wid = tid >> 6;
  const int h = wid >> 2;             // KV half
  const int w = wid & 3;
  const int l15 = lane & 15, l4 = lane >> 4;

  __shared__ __align__(16) char smem[131072];
  // group h region: smem + h*65536. lK dbuf 2x16KB at +0; lV dbuf 2x16KB at +32768.
  char* const gbase = smem + h * 65536;

  s16x8 qa[2];
#pragma unroll
  for (int ks = 0; ks < 2; ++ks)
    qa[ks] = *(const s16x8*)(Qg + ((size_t)b * 1024 + q0 + w * 16 + l15) * 64
                             + ks * 32 + l4 * 8);

  const u16* Kb = Kg + (size_t)b * 65536;
  const u16* Vb = Vg + (size_t)b * 65536;

  float l_run = 0.f;
  f32x4 oacc[4];
#pragma unroll
  for (int n = 0; n < 4; ++n) oacc[n] = (f32x4)(0.0f);

  auto kv_issue = [&](int tile, int buf) {   // 8 GLD16/wave: 4 K + 4 V
    const int pk0 = tile * 128;
#pragma unroll
    for (int jj = 0; jj < 4; ++jj)
      GLD16(Kb + (size_t)(pk0 + w * 32 + jj * 8) * 64 + lane * 8,
            gbase + buf * 16384 + (w * 4 + jj) * 1024);
#pragma unroll
    for (int jj = 0; jj < 4; ++jj)
      GLD16(Vb + (size_t)(w * 16 + jj * 4 + (lane >> 4)) * 1024 + pk0 + (lane & 15) * 8,
            gbase + 32768 + buf * 16384 + (w * 4 + jj) * 1024);
  };

  auto compute = [&](int buf) {
    const u16* kB = (const u16*)(gbase + buf * 16384);
    const u16* vB = (const u16*)(gbase + 32768 + buf * 16384);
    f32x4 sacc[8];
#pragma unroll
    for (int n = 0; n < 8; ++n) sacc[n] = (f32x4)(0.0f);
    __builtin_amdgcn_s_setprio(1);
#pragma unroll
    for (int ks = 0; ks < 2; ++ks) {
#pragma unroll
      for (int n = 0; n < 8; ++n) {
        int row = n * 16 + l15;
        s16x8 kv = *(const s16x8*)(kB + row * 64 +
                     (((ks * 4 + l4) ^ ((row >> 1) & 7)) << 3));
        sacc[n] = __builtin_amdgcn_mfma_f32_16x16x32_bf16(kv, qa[ks], sacc[n], 0, 0, 0);
      }
    }
    __builtin_amdgcn_s_setprio(0);

    // in-register softmax: lane holds P[pk][q=l15]; K rows pre-permuted so the 32
    // values are exactly this lane's PV A-fragment.
    unsigned c[8][2];
    float psum = 0.f;
#pragma unroll
    for (int n = 0; n < 8; ++n) {
      float e0 = exp2f(sacc[n][0]);
      float e1 = exp2f(sacc[n][1]);
      float e2 = exp2f(sacc[n][2]);
      float e3 = exp2f(sacc[n][3]);
      psum += (e0 + e1) + (e2 + e3);
      c[n][0] = cvt_pk_bf16(e0, e1);
      c[n][1] = cvt_pk_bf16(e2, e3);
    }
    psum += __shfl_xor(psum, 16);
    psum += __shfl_xor(psum, 32);
    l_run += psum;

    __builtin_amdgcn_s_setprio(1);
#pragma unroll
    for (int ks = 0; ks < 4; ++ks) {
      u32x4 t;
      t[0] = c[2 * ks][0];
      t[1] = c[2 * ks][1];
      t[2] = c[2 * ks + 1][0];
      t[3] = c[2 * ks + 1][1];
      s16x8 pfr = __builtin_bit_cast(s16x8, t);
#pragma unroll
      for (int n = 0; n < 4; ++n) {
        int row = n * 16 + l15;
        s16x8 vv = *(const s16x8*)(vB + row * 128 +
                     (((ks * 4 + l4) ^ ((row & 7) << 1)) << 3));
        oacc[n] = __builtin_amdgcn_mfma_f32_16x16x32_bf16(pfr, vv, oacc[n], 0, 0, 0);
      }
    }
    __builtin_amdgcn_s_setprio(0);
  };

  const int t0 = h * 4;
  kv_issue(t0, 0);
  kv_issue(t0 + 1, 1);
  asm volatile("s_waitcnt vmcnt(8)" ::: "memory");
  __builtin_amdgcn_sched_barrier(0);
  __builtin_amdgcn_s_barrier();
  __builtin_amdgcn_sched_barrier(0);

  for (int ic = 0; ic < 4; ++ic) {
    compute(ic & 1);
    if (ic < 3) {
      __builtin_amdgcn_sched_barrier(0);
      __builtin_amdgcn_s_barrier();        // all waves done reading buf ic&1
      __builtin_amdgcn_sched_barrier(0);
      if (ic + 2 < 4) {
        kv_issue(t0 + ic + 2, ic & 1);
        asm volatile("s_waitcnt vmcnt(8)" ::: "memory");   // tile ic+1 complete
      } else {
        asm volatile("s_waitcnt vmcnt(0)" ::: "memory");   // tile 3 complete
      }
      __builtin_amdgcn_sched_barrier(0);
      __builtin_amdgcn_s_barrier();        // tile ic+1 visible to all waves
      __builtin_amdgcn_sched_barrier(0);
    }
  }

  // redistribute l: lane needs l for q = l4*4+r, held by lane (l4*4+r) of same wave
  float lr[4];
#pragma unroll
  for (int r = 0; r < 4; ++r) lr[r] = __shfl(l_run, l4 * 4 + r);

  // in-block merge of the two halves through LDS (reuses group-0 K region)
  __syncthreads();
  if (h == 1) {
    float* mrg = (float*)smem + (tid - 256) * 20;
#pragma unroll
    for (int n = 0; n < 4; ++n) *(f32x4*)(mrg + n * 4) = oacc[n];
#pragma unroll
    for (int r = 0; r < 4; ++r) mrg[16 + r] = lr[r];
  }
  __syncthreads();
  if (h == 0) {
    const float* mrg = (const float*)smem + tid * 20;
    float lt[4];
#pragma unroll
    for (int r = 0; r < 4; ++r) lt[r] = lr[r] + mrg[16 + r];
#pragma unroll
    for (int n = 0; n < 4; ++n) {
      f32x4 o1 = *(const f32x4*)(mrg + n * 4);
      float4 o;
      o.x = (oacc[n][0] + o1[0]) / lt[0];
      o.y = (oacc[n][1] + o1[1]) / lt[1];
      o.z = (oacc[n][2] + o1[2]) / lt[2];
      o.w = (oacc[n][3] + o1[3]) / lt[3];
      *(float4*)(out + ((size_t)b * 64 + n * 16 + l15) * 1024 + q0 + w * 16 + l4 * 4) = o;
    }
  }
}

extern "C" void kernel_launch(void* const* d_in, const int* in_sizes, int n_in,
                              void* d_out, int out_size, void* d_ws, size_t ws_size,
                              hipStream_t stream) {
  const float* x  = (const float*)d_in[0];
  const float* wq = (const float*)d_in[1];
  const float* bq = (const float*)d_in[2];
  const float* wk = (const float*)d_in[3];
  const float* bk = (const float*)d_in[4];
  const float* wv = (const float*)d_in[5];
  const float* bv = (const float*)d_in[6];
  float* out = (float*)d_out;

  u16* Qo  = (u16*)d_ws;                              // [16][1024][64] bf16 (scaled)
  u16* Ko  = Qo + (size_t)16 * 1024 * 64;             // [16][1024][64] bf16, permuted+swizzled
  u16* Vt  = Ko + (size_t)16 * 1024 * 64;             // [16][64][1024] bf16, swizzled
  u16* Wpk = Vt + (size_t)16 * 1024 * 64;             // [32][192][64] bf16 prepacked

  prepack_w<<<192, 256, 0, stream>>>(wq, wk, wv, Wpk);
  qkv_proj<<<256, 512, 0, stream>>>(x, Wpk, bq, bk, bv, Qo, Ko, Vt);
  attn_kernel<<<256, 512, 0, stream>>>(Qo, Ko, Vt, out);
}